// Round 5
// baseline (111.663 us; speedup 1.0000x reference)
//
#include <hip/hip_runtime.h>

typedef int   i32x4  __attribute__((ext_vector_type(4)));
typedef int   i32x8  __attribute__((ext_vector_type(8)));
typedef float f32x16 __attribute__((ext_vector_type(16)));

#define B_ROWS 4096
#define NROWS  8192
#define DDIM   512
// exp(sim/T) = exp2(sim * (1/T)/ln2), T=0.5 -> 2/ln2
#define SCALE2 2.8853900817779268f
// e8m0 scale 127 = 2^0 = 1.0 in every byte -> scaled MFMA == plain fp8 MFMA
#define SCL1   0x7f7f7f7f

// zq layout (v2, bank-conflict-free MX fragments): per 32-row group (rg32 =
// row>>5), 16 KB = 8 k-groups (kg = k>>6) x 2 KB segments. Within a segment,
// lane id l = (k>>5)*32 + (row&31); the lane's 32 fragment bytes are split:
//   bytes k%32 in [0,16)  at  seg +    0 + l*16 + (k&15)
//   bytes k%32 in [16,32) at  seg + 1024 + l*16 + (k&15)
// so an MFMA A/B fragment is TWO LINEAR ds_read_b128 (zero bank conflict,
// verified R2: SQ_LDS_BANK_CONFLICT 2.15M -> 16.6K), and global_load_lds
// staging stays linear (permutation baked into zq by normalize).
// scratch: 64x64 grid of 128-float cells, each written EXACTLY once.

// ---------------- normalize: fp32 -> fp8 e4m3, 32-row blocks, LDS-repack ---------
__global__ __launch_bounds__(256) void normalize_kernel(
    const float* __restrict__ h1, const float* __restrict__ h2,
    unsigned char* __restrict__ zq, float* __restrict__ out) {
  __shared__ __align__(16) unsigned char tile[16384];
  if (blockIdx.x == 0 && threadIdx.x == 0) out[0] = 0.0f;

  const int wave = threadIdx.x >> 6;
  const int lane = threadIdx.x & 63;
  const int rb = blockIdx.x;            // 32-row group
  // lane covers k = lane*8 .. lane*8+7
  const int kg = lane >> 3;             // k-group of 64
  const int q  = (lane >> 1) & 1;       // (k>>4)&1: which 16B half-page
  const int h  = (lane >> 2) & 1;       // (k>>5)&1: k-half of 32 (lane-id bit 5)
  const int k8 = (lane & 1) * 8;        // (k&15) byte offset within 16B unit

  #pragma unroll
  for (int it = 0; it < 8; ++it) {
    const int r = it * 4 + wave;        // 0..31, one full row per wave
    const int row = rb * 32 + r;
    const float* src = (row < B_ROWS) ? (h1 + (size_t)row * DDIM)
                                      : (h2 + (size_t)(row - B_ROWS) * DDIM);
    float4 v0 = *(const float4*)(src + lane * 8);
    float4 v1 = *(const float4*)(src + lane * 8 + 4);
    float ss = v0.x*v0.x + v0.y*v0.y + v0.z*v0.z + v0.w*v0.w
             + v1.x*v1.x + v1.y*v1.y + v1.z*v1.z + v1.w*v1.w;
    #pragma unroll
    for (int m = 1; m <= 32; m <<= 1) ss += __shfl_xor(ss, m);
    float sc = 1.0f / fmaxf(sqrtf(ss), 1e-8f);
    int lo = 0, hi = 0;
    lo = __builtin_amdgcn_cvt_pk_fp8_f32(v0.x*sc, v0.y*sc, lo, 0);
    lo = __builtin_amdgcn_cvt_pk_fp8_f32(v0.z*sc, v0.w*sc, lo, 1);
    hi = __builtin_amdgcn_cvt_pk_fp8_f32(v1.x*sc, v1.y*sc, hi, 0);
    hi = __builtin_amdgcn_cvt_pk_fp8_f32(v1.z*sc, v1.w*sc, hi, 1);
    *(int2*)(tile + kg * 2048 + q * 1024 + (h * 32 + r) * 16 + k8) =
        make_int2(lo, hi);
  }
  __syncthreads();
  const size_t base = (size_t)rb * 16384;
  #pragma unroll
  for (int j = 0; j < 4; ++j)
    *(int4*)(zq + base + j * 4096 + threadIdx.x * 16) =
        *(const int4*)(tile + j * 4096 + threadIdx.x * 16);
}

// ---------------- fused sim GEMM (MX-fp8, unit scales) + exp + row-sum ------------
// History: (256,4)->287MB spill,121us. (256,3)->193MB spill,94us. (256,2)->no
// spill but latency-bound at 66us (MfmaUtil 9.7%, VALU 23%, HBM 3.7%, occ 17%;
// 2 waves/SIMD can't hide ds_read/MFMA dep latency — R4's vmcnt pipeline changed
// NOTHING, so the stall is in-phase, not at the staging drain). R5: 512-thread /
// 8-wave blocks, per-wave tile 64x32 -> acc 32 + frags 24 regs, cap 128
// ((512,4)) -> 2 blocks x 8 waves = 16 waves/CU = 4 waves/SIMD, 2x parallelism.
// Spill canary: WRITE_SIZE (~2 MB when clean).
#define ASM_VMCNT4() asm volatile("s_waitcnt vmcnt(4)" ::: "memory")
#define ASM_VMCNT0() asm volatile("s_waitcnt vmcnt(0)" ::: "memory")
#define BARRIER() do { asm volatile("" ::: "memory"); \
                       __builtin_amdgcn_s_barrier(); \
                       asm volatile("" ::: "memory"); } while (0)

__global__ __launch_bounds__(512, 4) void simexp_kernel(
    const unsigned char* __restrict__ zq, float* __restrict__ scratch,
    float* __restrict__ pos) {
  __shared__ __align__(16) unsigned char As[32768];  // 2 bufs x 8 segs x 2 KB
  __shared__ __align__(16) unsigned char Bs[32768];
  __shared__ float rp[512];   // row partials: slot lrow*4 + wn
  __shared__ float cp[256];   // col partials: slot lcol*2 + wm

  const int tid  = threadIdx.x;
  const int wave = tid >> 6;           // 0..7
  const int lane = tid & 63;
  const int wm = wave >> 2;            // 0..1: row half (64 rows)
  const int wn = wave & 3;             // 0..3: col quarter (32 cols)
  const int l31 = lane & 31;
  const int hi5 = lane >> 5;

  // unrank triangular block index: t = bi*(bi+1)/2 + bj, bi >= bj
  int t  = blockIdx.x;
  int bi = (int)((sqrtf(8.0f * (float)t + 1.0f) - 1.0f) * 0.5f);
  while ((bi + 1) * (bi + 2) / 2 <= t) ++bi;
  while (bi * (bi + 1) / 2 > t) --bi;
  int bj = t - bi * (bi + 1) / 2;
  const int rowBlk = bi * 128;
  const int colBlk = bj * 128;
  const bool isDiag = (bi == bj);

  const unsigned char* aBase = zq + (size_t)bi * 65536;  // 4 rg32 x 8 kg x 2 KB
  const unsigned char* bBase = zq + (size_t)bj * 65536;

  f32x16 acc[2] = {};

  // 32 x 1KB units per quarter (16 A + 16 B); 8 waves x 4 units each.
  #define STAGE(hh, bb) do {                                                   \
    _Pragma("unroll")                                                          \
    for (int i = 0; i < 4; ++i) {                                              \
      const int u4 = wave * 4 + i;       /* 0..31, wave-uniform A/B split */   \
      const int m = u4 & 15;                                                   \
      const int s = m >> 1;                                                    \
      const int rg32 = s >> 1, gl = s & 1;                                     \
      const size_t goff =                                                      \
          (size_t)((rg32 * 8 + (hh) * 2 + gl) * 2048 + (m & 1) * 1024 + lane * 16); \
      const size_t loff = (size_t)((bb) * 16384 + m * 1024 + lane * 16);       \
      const unsigned char* gsrc = (u4 < 16 ? aBase : bBase) + goff;            \
      unsigned char* ldst = (u4 < 16 ? (unsigned char*)As : (unsigned char*)Bs) + loff; \
      __builtin_amdgcn_global_load_lds(                                        \
          (const __attribute__((address_space(1))) unsigned int*)gsrc,         \
          (__attribute__((address_space(3))) unsigned int*)ldst, 16, 0, 0);    \
    }                                                                          \
  } while (0)

  STAGE(0, 0);
  #pragma unroll
  for (int h = 0; h < 4; ++h) {              // K-quarter: kg = h*2, h*2+1
    if (h < 3) {
      STAGE(h + 1, (h + 1) & 1);
      ASM_VMCNT4();                          // quarter-h loads landed; h+1 flying
    } else {
      ASM_VMCNT0();
    }
    BARRIER();                               // buf[h&1] visible to all waves

    const int bb = (h & 1) * 16384;
    #pragma unroll
    for (int gl = 0; gl < 2; ++gl) {         // K-64 step within quarter
      i32x8 afr[2], bfr;
      #pragma unroll
      for (int rt = 0; rt < 2; ++rt) {
        const unsigned char* p =
            As + bb + (size_t)((wm * 2 + rt) * 2 + gl) * 2048 + lane * 16;
        i32x4 lo = *(const i32x4*)p;
        i32x4 hi = *(const i32x4*)(p + 1024);
        afr[rt][0] = lo[0]; afr[rt][1] = lo[1]; afr[rt][2] = lo[2]; afr[rt][3] = lo[3];
        afr[rt][4] = hi[0]; afr[rt][5] = hi[1]; afr[rt][6] = hi[2]; afr[rt][7] = hi[3];
      }
      {
        const unsigned char* p =
            Bs + bb + (size_t)(wn * 2 + gl) * 2048 + lane * 16;
        i32x4 lo = *(const i32x4*)p;
        i32x4 hi = *(const i32x4*)(p + 1024);
        bfr[0] = lo[0]; bfr[1] = lo[1]; bfr[2] = lo[2]; bfr[3] = lo[3];
        bfr[4] = hi[0]; bfr[5] = hi[1]; bfr[6] = hi[2]; bfr[7] = hi[3];
      }
      acc[0] = __builtin_amdgcn_mfma_scale_f32_32x32x64_f8f6f4(
          afr[0], bfr, acc[0], 0, 0, 0, SCL1, 0, SCL1);
      acc[1] = __builtin_amdgcn_mfma_scale_f32_32x32x64_f8f6f4(
          afr[1], bfr, acc[1], 0, 0, 0, SCL1, 0, SCL1);
    }
    // ds_reads are consumed by MFMAs (lgkmcnt-drained) before this barrier, so
    // buf[h&1] is safe to overwrite by STAGE(h+2) afterwards.
    if (h < 3) BARRIER();
  }

  // ---- epilogue: exp2 -> unique-slot plain LDS writes -> 1 barrier -> stores ----
  // 32x32 C/D layout: col = lane&31, row = (reg&3) + 8*(reg>>2) + 4*(lane>>5)
  const bool posBlk = (bi - bj == 32);  // contains the +B diagonal
  float colpart = 0.f;
  #pragma unroll
  for (int rt = 0; rt < 2; ++rt) {
    #pragma unroll
    for (int reg = 0; reg < 16; ++reg) {
      const int lrow = wm * 64 + rt * 32 + (reg & 3) + 8 * (reg >> 2) + 4 * hi5;
      const int grow = rowBlk + lrow;
      const int gcol = colBlk + wn * 32 + l31;
      float sv = acc[rt][reg];
      float e = exp2f(sv * SCALE2);
      if (isDiag && grow == gcol) e = 0.f;
      if (posBlk && grow - B_ROWS == gcol) pos[gcol] = sv;
      colpart += e;
      float s = e;
      s += __shfl_xor(s, 1);
      s += __shfl_xor(s, 2);
      s += __shfl_xor(s, 4);
      s += __shfl_xor(s, 8);
      s += __shfl_xor(s, 16);
      if (l31 == 0) rp[lrow * 4 + wn] = s;          // single writer per slot
    }
  }
  colpart += __shfl_xor(colpart, 32);               // combine row-halves, same col
  if (hi5 == 0) cp[(wn * 32 + l31) * 2 + wm] = colpart;  // single writer
  __syncthreads();
  if (tid < 128) {
    scratch[(size_t)(bi * 64 + bj) * 128 + tid] =
        rp[tid * 4] + rp[tid * 4 + 1] + rp[tid * 4 + 2] + rp[tid * 4 + 3];
  } else if (tid < 256 && !isDiag) {
    const int c = tid - 128;
    scratch[(size_t)(bj * 64 + bi) * 128 + c] = cp[c * 2] + cp[c * 2 + 1];
  }
}

// ---------------- finalize: rowsum from scratch; loss mean ------------------------
__global__ __launch_bounds__(256) void finalize_kernel(
    const float* __restrict__ scratch, const float* __restrict__ pos,
    float* __restrict__ out) {
  __shared__ float red[4];
  const int gid = blockIdx.x * 256 + threadIdx.x;
  const int band = gid >> 7, r = gid & 127;
  const float* base = scratch + (size_t)band * 64 * 128 + r;
  float s = 0.f;
  #pragma unroll 8
  for (int c = 0; c < 64; ++c) s += base[c * 128];
  float loss = __logf(s) - 2.0f * pos[gid & (B_ROWS - 1)];
  #pragma unroll
  for (int m = 1; m <= 32; m <<= 1) loss += __shfl_xor(loss, m);
  const int wave = threadIdx.x >> 6;
  const int lane = threadIdx.x & 63;
  if (lane == 0) red[wave] = loss;
  __syncthreads();
  if (threadIdx.x == 0)
    atomicAdd(out, (red[0] + red[1] + red[2] + red[3]) * (1.0f / NROWS));
}

extern "C" void kernel_launch(void* const* d_in, const int* in_sizes, int n_in,
                              void* d_out, int out_size, void* d_ws, size_t ws_size,
                              hipStream_t stream) {
  const float* h1 = (const float*)d_in[0];
  const float* h2 = (const float*)d_in[1];
  float* out = (float*)d_out;
  unsigned char* zq = (unsigned char*)d_ws;                        // 4 MiB fp8
  float* scratch = (float*)((char*)d_ws + (size_t)NROWS * DDIM);   // 2 MiB
  float* pos     = scratch + 64 * 64 * 128;                        // 16 KiB

  normalize_kernel<<<NROWS / 32, 256, 0, stream>>>(h1, h2, zq, out);
  simexp_kernel<<<64 * 65 / 2, 512, 0, stream>>>(zq, scratch, pos);
  finalize_kernel<<<NROWS / 256, 256, 0, stream>>>(scratch, pos, out);
}

// Round 6
// 89.776 us; speedup vs baseline: 1.2438x; 1.2438x over previous
//
#include <hip/hip_runtime.h>

typedef int   i32x4  __attribute__((ext_vector_type(4)));
typedef int   i32x8  __attribute__((ext_vector_type(8)));
typedef float f32x16 __attribute__((ext_vector_type(16)));

#define B_ROWS 4096
#define NROWS  8192
#define DDIM   512
// exp(sim/T) = exp2(sim * (1/T)/ln2), T=0.5 -> 2/ln2
#define SCALE2 2.8853900817779268f
// e8m0 scale 127 = 2^0 = 1.0 in every byte -> scaled MFMA == plain fp8 MFMA
#define SCL1   0x7f7f7f7f

// zq layout (v2, unchanged): per 32-row group (rg32 = row>>5), 16 KB = 8
// k-groups (kg = k>>6) x 2 KB segments; lane l = (k>>5)*32 + (row&31) owns
// 16 B at seg+l*16 (k%32 in [0,16)) and 16 B at seg+1024+l*16 (k%32 in [16,32)).
// MFMA A/B fragment = two LINEAR ds_read_b128, zero bank conflict (verified R2).
//
// scratch (v3): chunk-major [128 chunks of 64 cols][8192 rows], 4 MB.
// Block (bi, bj2) covers rows [bi*128,+128) x cols [bj2*64,+64), bj2 <= 2*bi+1.
//   rp  -> scratch[bj2][bi*128 + r]        (row-sums, all blocks)
//   cp  -> scratch[2*bi + wm][bj2*64 + c]  (mirrored col-sums, split by row-half;
//                                           strictly-lower blocks only)
// Every slot written exactly once; no init, no atomics.

// ---------------- normalize: fp32 -> fp8 e4m3, 32-row blocks, LDS-repack ---------
__global__ __launch_bounds__(256) void normalize_kernel(
    const float* __restrict__ h1, const float* __restrict__ h2,
    unsigned char* __restrict__ zq, float* __restrict__ out) {
  __shared__ __align__(16) unsigned char tile[16384];
  if (blockIdx.x == 0 && threadIdx.x == 0) out[0] = 0.0f;

  const int wave = threadIdx.x >> 6;
  const int lane = threadIdx.x & 63;
  const int rb = blockIdx.x;            // 32-row group
  // lane covers k = lane*8 .. lane*8+7
  const int kg = lane >> 3;             // k-group of 64
  const int q  = (lane >> 1) & 1;       // (k>>4)&1: which 16B half-page
  const int h  = (lane >> 2) & 1;       // (k>>5)&1: k-half of 32 (lane-id bit 5)
  const int k8 = (lane & 1) * 8;        // (k&15) byte offset within 16B unit

  #pragma unroll
  for (int it = 0; it < 8; ++it) {
    const int r = it * 4 + wave;        // 0..31, one full row per wave
    const int row = rb * 32 + r;
    const float* src = (row < B_ROWS) ? (h1 + (size_t)row * DDIM)
                                      : (h2 + (size_t)(row - B_ROWS) * DDIM);
    float4 v0 = *(const float4*)(src + lane * 8);
    float4 v1 = *(const float4*)(src + lane * 8 + 4);
    float ss = v0.x*v0.x + v0.y*v0.y + v0.z*v0.z + v0.w*v0.w
             + v1.x*v1.x + v1.y*v1.y + v1.z*v1.z + v1.w*v1.w;
    #pragma unroll
    for (int m = 1; m <= 32; m <<= 1) ss += __shfl_xor(ss, m);
    float sc = 1.0f / fmaxf(sqrtf(ss), 1e-8f);
    int lo = 0, hi = 0;
    lo = __builtin_amdgcn_cvt_pk_fp8_f32(v0.x*sc, v0.y*sc, lo, 0);
    lo = __builtin_amdgcn_cvt_pk_fp8_f32(v0.z*sc, v0.w*sc, lo, 1);
    hi = __builtin_amdgcn_cvt_pk_fp8_f32(v1.x*sc, v1.y*sc, hi, 0);
    hi = __builtin_amdgcn_cvt_pk_fp8_f32(v1.z*sc, v1.w*sc, hi, 1);
    *(int2*)(tile + kg * 2048 + q * 1024 + (h * 32 + r) * 16 + k8) =
        make_int2(lo, hi);
  }
  __syncthreads();
  const size_t base = (size_t)rb * 16384;
  #pragma unroll
  for (int j = 0; j < 4; ++j)
    *(int4*)(zq + base + j * 4096 + threadIdx.x * 16) =
        *(const int4*)(tile + j * 4096 + threadIdx.x * 16);
}

// ---------------- fused sim GEMM (MX-fp8, unit scales) + exp + row-sum ------------
// Register history: 128-reg caps ((256,4),(512,4)) -> allocator splits arch/AGPR
// 64/64 -> spill (287/177 MB). (256,2)=no spill but 2 waves/SIMD latency-bound
// (66us, MfmaUtil 9.7%; vmcnt pipeline R4 changed nothing -> in-phase dep stalls).
// R6: 256thr/4-wave blocks, tile 128x64, per-wave 64x32 (acc 32 + frag 24 regs,
// demand ~110 << 170 cap from (256,3)) -> 3 independent blocks/CU = 3 waves/SIMD,
// matching R0's proven-40%-MfmaUtil occupancy. Spill canary: WRITE_SIZE (~4 MB).
#define ASM_VMCNT6() asm volatile("s_waitcnt vmcnt(6)" ::: "memory")
#define ASM_VMCNT0() asm volatile("s_waitcnt vmcnt(0)" ::: "memory")
#define BARRIER() do { asm volatile("" ::: "memory"); \
                       __builtin_amdgcn_s_barrier(); \
                       asm volatile("" ::: "memory"); } while (0)

__global__ __launch_bounds__(256, 3) void simexp_kernel(
    const unsigned char* __restrict__ zq, float* __restrict__ scratch,
    float* __restrict__ pos) {
  __shared__ __align__(16) unsigned char As[32768];  // 2 bufs x 8 segs x 2 KB
  __shared__ __align__(16) unsigned char Bs[16384];  // 2 bufs x 4 segs x 2 KB
  __shared__ float rp[256];   // row partials: slot lrow*2 + wn
  __shared__ float cp[128];   // col partials: slot lcol*2 + wm

  const int tid  = threadIdx.x;
  const int wave = tid >> 6;           // 0..3
  const int lane = tid & 63;
  const int wm = wave >> 1;            // 0..1: row half (64 rows)
  const int wn = wave & 1;             // 0..1: col half (32 cols)
  const int l31 = lane & 31;
  const int hi5 = lane >> 5;

  // unrank: blocks per row-band bi = 2*bi+2 (bj2 = 0..2*bi+1); cum = bi*(bi+1)
  int t  = blockIdx.x;
  int bi = (int)((sqrtf(4.0f * (float)t + 1.0f) - 1.0f) * 0.5f);
  while ((bi + 1) * (bi + 2) <= t) ++bi;
  while (bi * (bi + 1) > t) --bi;
  int bj2 = t - bi * (bi + 1);          // 0..2*bi+1 (64-col units)
  const bool diagRegion = (bj2 >= 2 * bi);
  const int dcol = 2 * bi - bj2;
  const bool posBlk = (dcol == 64) || (dcol == 63);  // contains the +B diagonal

  const unsigned char* aBase = zq + (size_t)bi  * 65536;  // 4 rg32 x 16 KB
  const unsigned char* bBase = zq + (size_t)bj2 * 32768;  // 2 rg32 x 16 KB

  f32x16 acc[2] = {};

  // 24 x 1KB units per quarter (16 A + 8 B); 4 waves x 6 units each.
  #define STAGE(hh, bb) do {                                                   \
    _Pragma("unroll")                                                          \
    for (int i = 0; i < 6; ++i) {                                              \
      const int u = wave * 6 + i;          /* 0..23, wave-uniform */           \
      const int isA = (u < 16);                                                \
      const int v = isA ? u : (u - 16);    /* A: 0..15, B: 0..7 */             \
      const int seg = v >> 1, half = v & 1;                                    \
      const int rgl = seg >> 1, gl = seg & 1;                                  \
      const size_t goff =                                                      \
          (size_t)((rgl * 8 + (hh) * 2 + gl) * 2048 + half * 1024 + lane * 16);\
      const unsigned char* gsrc = (isA ? aBase : bBase) + goff;                \
      unsigned char* ldst = isA ? (As + (bb) * 16384 + v * 1024 + lane * 16)   \
                                : (Bs + (bb) * 8192  + v * 1024 + lane * 16);  \
      __builtin_amdgcn_global_load_lds(                                        \
          (const __attribute__((address_space(1))) unsigned int*)gsrc,         \
          (__attribute__((address_space(3))) unsigned int*)ldst, 16, 0, 0);    \
    }                                                                          \
  } while (0)

  STAGE(0, 0);
  #pragma unroll
  for (int h = 0; h < 4; ++h) {              // K-quarter: kg = h*2, h*2+1
    if (h < 3) {
      STAGE(h + 1, (h + 1) & 1);
      ASM_VMCNT6();                          // quarter-h landed; h+1 in flight
    } else {
      ASM_VMCNT0();
    }
    BARRIER();                               // buf[h&1] visible to all waves

    const int ba = (h & 1) * 16384;
    const int bbf = (h & 1) * 8192;
    #pragma unroll
    for (int gl = 0; gl < 2; ++gl) {         // K-64 step within quarter
      i32x8 afr[2], bfr;
      #pragma unroll
      for (int rt = 0; rt < 2; ++rt) {
        const unsigned char* p =
            As + ba + (size_t)((wm * 2 + rt) * 2 + gl) * 2048 + lane * 16;
        i32x4 lo = *(const i32x4*)p;
        i32x4 hi = *(const i32x4*)(p + 1024);
        afr[rt][0] = lo[0]; afr[rt][1] = lo[1]; afr[rt][2] = lo[2]; afr[rt][3] = lo[3];
        afr[rt][4] = hi[0]; afr[rt][5] = hi[1]; afr[rt][6] = hi[2]; afr[rt][7] = hi[3];
      }
      {
        const unsigned char* p =
            Bs + bbf + (size_t)(wn * 2 + gl) * 2048 + lane * 16;
        i32x4 lo = *(const i32x4*)p;
        i32x4 hi = *(const i32x4*)(p + 1024);
        bfr[0] = lo[0]; bfr[1] = lo[1]; bfr[2] = lo[2]; bfr[3] = lo[3];
        bfr[4] = hi[0]; bfr[5] = hi[1]; bfr[6] = hi[2]; bfr[7] = hi[3];
      }
      acc[0] = __builtin_amdgcn_mfma_scale_f32_32x32x64_f8f6f4(
          afr[0], bfr, acc[0], 0, 0, 0, SCL1, 0, SCL1);
      acc[1] = __builtin_amdgcn_mfma_scale_f32_32x32x64_f8f6f4(
          afr[1], bfr, acc[1], 0, 0, 0, SCL1, 0, SCL1);
    }
    // ds_reads consumed (lgkmcnt-drained into MFMAs) before this barrier, so
    // buf[h&1] is safe for STAGE(h+2) afterwards.
    if (h < 3) BARRIER();
  }

  // ---- epilogue: exp2 -> unique-slot plain LDS writes -> 1 barrier -> stores ----
  // 32x32 C/D layout: col = lane&31, row = (reg&3) + 8*(reg>>2) + 4*(lane>>5)
  float colpart = 0.f;
  #pragma unroll
  for (int rt = 0; rt < 2; ++rt) {
    #pragma unroll
    for (int reg = 0; reg < 16; ++reg) {
      const int lrow = wm * 64 + rt * 32 + (reg & 3) + 8 * (reg >> 2) + 4 * hi5;
      const int grow = bi * 128 + lrow;
      const int gcol = bj2 * 64 + wn * 32 + l31;
      float sv = acc[rt][reg];
      float e = exp2f(sv * SCALE2);
      if (diagRegion && grow == gcol) e = 0.f;
      if (posBlk && grow - B_ROWS == gcol) pos[gcol] = sv;
      colpart += e;
      float s = e;
      s += __shfl_xor(s, 1);
      s += __shfl_xor(s, 2);
      s += __shfl_xor(s, 4);
      s += __shfl_xor(s, 8);
      s += __shfl_xor(s, 16);
      if (l31 == 0) rp[lrow * 2 + wn] = s;          // single writer per slot
    }
  }
  colpart += __shfl_xor(colpart, 32);   // add other hi5 half -> 64 rows (wm half)
  if (hi5 == 0) cp[(wn * 32 + l31) * 2 + wm] = colpart;  // single writer
  __syncthreads();
  if (tid < 128) {
    scratch[(size_t)bj2 * NROWS + bi * 128 + tid] = rp[tid * 2] + rp[tid * 2 + 1];
  } else if (!diagRegion) {
    const int c = tid - 128;                  // 0..127
    const int lcol = c & 63, wmv = c >> 6;    // mirrored: row bj2*64+lcol,
    scratch[(size_t)(2 * bi + wmv) * NROWS + bj2 * 64 + lcol] =
        cp[lcol * 2 + wmv];                   // chunk = 2*bi + row-half
  }
}

// ---------------- finalize: rowsum over 128 chunks; loss mean --------------------
__global__ __launch_bounds__(256) void finalize_kernel(
    const float* __restrict__ scratch, const float* __restrict__ pos,
    float* __restrict__ out) {
  __shared__ float red[4];
  const int r = blockIdx.x * 256 + threadIdx.x;   // one row per thread
  float s = 0.f;
  #pragma unroll 8
  for (int c = 0; c < 128; ++c) s += scratch[(size_t)c * NROWS + r];
  float loss = __logf(s) - 2.0f * pos[r & (B_ROWS - 1)];
  #pragma unroll
  for (int m = 1; m <= 32; m <<= 1) loss += __shfl_xor(loss, m);
  const int wave = threadIdx.x >> 6;
  const int lane = threadIdx.x & 63;
  if (lane == 0) red[wave] = loss;
  __syncthreads();
  if (threadIdx.x == 0)
    atomicAdd(out, (red[0] + red[1] + red[2] + red[3]) * (1.0f / NROWS));
}

extern "C" void kernel_launch(void* const* d_in, const int* in_sizes, int n_in,
                              void* d_out, int out_size, void* d_ws, size_t ws_size,
                              hipStream_t stream) {
  const float* h1 = (const float*)d_in[0];
  const float* h2 = (const float*)d_in[1];
  float* out = (float*)d_out;
  unsigned char* zq = (unsigned char*)d_ws;                        // 4 MiB fp8
  float* scratch = (float*)((char*)d_ws + (size_t)NROWS * DDIM);   // 4 MiB
  float* pos     = scratch + 128 * NROWS;                          // 16 KiB

  normalize_kernel<<<NROWS / 32, 256, 0, stream>>>(h1, h2, zq, out);
  simexp_kernel<<<64 * 65, 256, 0, stream>>>(zq, scratch, pos);    // 4160 blocks
  finalize_kernel<<<NROWS / 256, 256, 0, stream>>>(scratch, pos, out);
}

// Round 7
// 61.314 us; speedup vs baseline: 1.8212x; 1.4642x over previous
//
#include <hip/hip_runtime.h>

typedef int   i32x4  __attribute__((ext_vector_type(4)));
typedef int   i32x8  __attribute__((ext_vector_type(8)));
typedef float f32x16 __attribute__((ext_vector_type(16)));

#define B_ROWS 4096
#define NROWS  8192
#define DDIM   512
// exp(sim/T) = exp2(sim * (1/T)/ln2), T=0.5 -> 2/ln2
#define SCALE2 2.8853900817779268f
// e8m0 scale 127 = 2^0 = 1.0 in every byte -> scaled MFMA == plain fp8 MFMA
#define SCL1   0x7f7f7f7f

// zq layout (v2, unchanged, verified R2/R3): per 32-row group (rg32 = row>>5),
// 16 KB = 8 k-groups (kg = k>>6) x 2 KB segments; lane l = (k>>5)*32 + (row&31)
// owns 16 B at seg+l*16 (k%32 in [0,16)) and 16 B at seg+1024+l*16 (k%32 in
// [16,32)). An MFMA A/B fragment = two LINEAR 16B loads at lane*16.
//
// R7 structural change: zq (4 MB) fits in one XCD's L2 -> LDS staging is pure
// overhead (Common-mistake #7 / m169: drop staging for L2-fit data). K-loop now
// loads fragments DIRECTLY from zq via global_load_dwordx4 — no As/Bs, no
// barriers, no lockstep; each wave is an independent straight-line pipeline.
// Epilogue: 160-shfl/thread row-reduce replaced by split-halves butterfly
// (16 shfl per 16 values over 32 lanes).
//
// scratch (R3 scheme): 64x64 grid of 128-float cells, each written EXACTLY once
// (row-parts of block (bi,bj) -> cell (bi,bj); col-parts -> cell (bj,bi)).

// ---------------- normalize: fp32 -> fp8 e4m3, 32-row blocks, LDS-repack ---------
__global__ __launch_bounds__(256) void normalize_kernel(
    const float* __restrict__ h1, const float* __restrict__ h2,
    unsigned char* __restrict__ zq, float* __restrict__ out) {
  __shared__ __align__(16) unsigned char tile[16384];
  if (blockIdx.x == 0 && threadIdx.x == 0) out[0] = 0.0f;

  const int wave = threadIdx.x >> 6;
  const int lane = threadIdx.x & 63;
  const int rb = blockIdx.x;            // 32-row group
  // lane covers k = lane*8 .. lane*8+7
  const int kg = lane >> 3;             // k-group of 64
  const int q  = (lane >> 1) & 1;       // (k>>4)&1: which 16B half-page
  const int h  = (lane >> 2) & 1;       // (k>>5)&1: k-half of 32 (lane-id bit 5)
  const int k8 = (lane & 1) * 8;        // (k&15) byte offset within 16B unit

  #pragma unroll
  for (int it = 0; it < 8; ++it) {
    const int r = it * 4 + wave;        // 0..31, one full row per wave
    const int row = rb * 32 + r;
    const float* src = (row < B_ROWS) ? (h1 + (size_t)row * DDIM)
                                      : (h2 + (size_t)(row - B_ROWS) * DDIM);
    float4 v0 = *(const float4*)(src + lane * 8);
    float4 v1 = *(const float4*)(src + lane * 8 + 4);
    float ss = v0.x*v0.x + v0.y*v0.y + v0.z*v0.z + v0.w*v0.w
             + v1.x*v1.x + v1.y*v1.y + v1.z*v1.z + v1.w*v1.w;
    #pragma unroll
    for (int m = 1; m <= 32; m <<= 1) ss += __shfl_xor(ss, m);
    float sc = 1.0f / fmaxf(sqrtf(ss), 1e-8f);
    int lo = 0, hi = 0;
    lo = __builtin_amdgcn_cvt_pk_fp8_f32(v0.x*sc, v0.y*sc, lo, 0);
    lo = __builtin_amdgcn_cvt_pk_fp8_f32(v0.z*sc, v0.w*sc, lo, 1);
    hi = __builtin_amdgcn_cvt_pk_fp8_f32(v1.x*sc, v1.y*sc, hi, 0);
    hi = __builtin_amdgcn_cvt_pk_fp8_f32(v1.z*sc, v1.w*sc, hi, 1);
    *(int2*)(tile + kg * 2048 + q * 1024 + (h * 32 + r) * 16 + k8) =
        make_int2(lo, hi);
  }
  __syncthreads();
  const size_t base = (size_t)rb * 16384;
  #pragma unroll
  for (int j = 0; j < 4; ++j)
    *(int4*)(zq + base + j * 4096 + threadIdx.x * 16) =
        *(const int4*)(tile + j * 4096 + threadIdx.x * 16);
}

// ---------------- fused sim GEMM (MX-fp8, direct-from-L2) + exp + row-sum --------
// History: LDS-staged variants all 66-121us, every pipe idle (MfmaUtil <10%) —
// barrier-lockstep latency. R7: barrier-free K-loop, fragments straight from L2.
// Per-wave 64x64: acc 64 regs + frags 32 — spill-free at (256,2) (R3-verified).
// Spill canary: WRITE_SIZE (~2.1 MB when clean).
__global__ __launch_bounds__(256, 2) void simexp_kernel(
    const unsigned char* __restrict__ zq, float* __restrict__ scratch,
    float* __restrict__ pos) {
  __shared__ float rp[256];   // row partials: slot lrow*2 + wn
  __shared__ float cp[256];   // col partials: slot lcol*2 + wm

  const int tid  = threadIdx.x;
  const int wave = tid >> 6;
  const int lane = tid & 63;
  const int wm = wave >> 1, wn = wave & 1;
  const int l31 = lane & 31;
  const int hi5 = lane >> 5;

  // unrank triangular block index: t = bi*(bi+1)/2 + bj, bi >= bj
  int t  = blockIdx.x;
  int bi = (int)((sqrtf(8.0f * (float)t + 1.0f) - 1.0f) * 0.5f);
  while ((bi + 1) * (bi + 2) / 2 <= t) ++bi;
  while (bi * (bi + 1) / 2 > t) --bi;
  int bj = t - bi * (bi + 1) / 2;
  const int rowBlk = bi * 128;
  const int colBlk = bj * 128;
  const bool isDiag = (bi == bj);

  // wave's A rows: rg32 = bi*4 + wm*2 + rt ; B cols: rg32 = bj*4 + wn*2 + ct
  const unsigned char* aW = zq + (size_t)bi * 65536 + (size_t)(wm * 2) * 16384
                               + (size_t)lane * 16;
  const unsigned char* bW = zq + (size_t)bj * 65536 + (size_t)(wn * 2) * 16384
                               + (size_t)lane * 16;

  f32x16 acc[2][2] = {};

  #pragma unroll
  for (int kk = 0; kk < 8; ++kk) {           // K-64 step; no barriers anywhere
    i32x8 afr[2], bfr[2];
    #pragma unroll
    for (int rt = 0; rt < 2; ++rt) {
      const unsigned char* p = aW + (size_t)rt * 16384 + kk * 2048;
      i32x4 lo = *(const i32x4*)p;
      i32x4 hi = *(const i32x4*)(p + 1024);
      afr[rt][0] = lo[0]; afr[rt][1] = lo[1]; afr[rt][2] = lo[2]; afr[rt][3] = lo[3];
      afr[rt][4] = hi[0]; afr[rt][5] = hi[1]; afr[rt][6] = hi[2]; afr[rt][7] = hi[3];
    }
    #pragma unroll
    for (int ct = 0; ct < 2; ++ct) {
      const unsigned char* p = bW + (size_t)ct * 16384 + kk * 2048;
      i32x4 lo = *(const i32x4*)p;
      i32x4 hi = *(const i32x4*)(p + 1024);
      bfr[ct][0] = lo[0]; bfr[ct][1] = lo[1]; bfr[ct][2] = lo[2]; bfr[ct][3] = lo[3];
      bfr[ct][4] = hi[0]; bfr[ct][5] = hi[1]; bfr[ct][6] = hi[2]; bfr[ct][7] = hi[3];
    }
    #pragma unroll
    for (int rt = 0; rt < 2; ++rt)
      #pragma unroll
      for (int ct = 0; ct < 2; ++ct)
        acc[rt][ct] = __builtin_amdgcn_mfma_scale_f32_32x32x64_f8f6f4(
            afr[rt], bfr[ct], acc[rt][ct], 0, 0, 0, SCL1, 0, SCL1);
  }

  // ---- epilogue: exp2 in place -> butterfly row-reduce -> 1 barrier -> stores ----
  // 32x32 C/D layout: col = lane&31, row = (reg&3) + 8*(reg>>2) + 4*(lane>>5)
  const bool posBlk = (bi - bj == 32);  // contains the +B diagonal
  float colpart[2] = {0.f, 0.f};
  #pragma unroll
  for (int rt = 0; rt < 2; ++rt)
    #pragma unroll
    for (int ct = 0; ct < 2; ++ct)
      #pragma unroll
      for (int reg = 0; reg < 16; ++reg) {
        const int lrow = wm * 64 + rt * 32 + (reg & 3) + 8 * (reg >> 2) + 4 * hi5;
        const int grow = rowBlk + lrow;
        const int gcol = colBlk + wn * 64 + ct * 32 + l31;
        float sv = acc[rt][ct][reg];
        float e = exp2f(sv * SCALE2);
        if (isDiag && grow == gcol) e = 0.f;
        if (posBlk && grow - B_ROWS == gcol) pos[gcol] = sv;
        acc[rt][ct][reg] = e;
        colpart[ct] += e;
      }

  // row sums: per rt, 16 values (ct-pairs pre-added) over 32 lanes in 16 shfl.
  // After the butterfly, lane l31 holds the row-sum for
  //   reg16 = 8*(l&1) + 4*((l>>1)&1) + 2*((l>>2)&1) + ((l>>3)&1)
  #pragma unroll
  for (int rt = 0; rt < 2; ++rt) {
    float v[16];
    #pragma unroll
    for (int reg = 0; reg < 16; ++reg)
      v[reg] = acc[rt][0][reg] + acc[rt][1][reg];   // same row, cols +-32
    #pragma unroll
    for (int st = 0; st < 4; ++st) {
      const int m = 1 << st;
      const int n = 8 >> st;
      #pragma unroll
      for (int i = 0; i < n; ++i) {
        float send = (l31 & m) ? v[i] : v[i + n];
        float keep = (l31 & m) ? v[i + n] : v[i];
        v[i] = keep + __shfl_xor(send, m);
      }
    }
    v[0] += __shfl_xor(v[0], 16);                   // same reg16 both sides
    const int reg16 = 8 * (l31 & 1) + 4 * ((l31 >> 1) & 1)
                    + 2 * ((l31 >> 2) & 1) + ((l31 >> 3) & 1);
    const int lrow = wm * 64 + rt * 32 + (reg16 & 3) + 8 * (reg16 >> 2) + 4 * hi5;
    if (l31 < 16) rp[lrow * 2 + wn] = v[0];         // single writer per slot
  }
  #pragma unroll
  for (int ct = 0; ct < 2; ++ct) {
    float c = colpart[ct];
    c += __shfl_xor(c, 32);                         // combine hi5 halves, same col
    if (hi5 == 0) cp[(wn * 64 + ct * 32 + l31) * 2 + wm] = c;  // single writer
  }
  __syncthreads();
  if (tid < 128) {
    scratch[(size_t)(bi * 64 + bj) * 128 + tid] = rp[tid * 2] + rp[tid * 2 + 1];
  } else if (!isDiag) {
    const int c = tid - 128;
    scratch[(size_t)(bj * 64 + bi) * 128 + c] = cp[c * 2] + cp[c * 2 + 1];
  }
}

// ---------------- finalize: rowsum from scratch; loss mean ------------------------
__global__ __launch_bounds__(256) void finalize_kernel(
    const float* __restrict__ scratch, const float* __restrict__ pos,
    float* __restrict__ out) {
  __shared__ float red[4];
  const int gid = blockIdx.x * 256 + threadIdx.x;
  const int band = gid >> 7, r = gid & 127;
  const float* base = scratch + (size_t)band * 64 * 128 + r;
  float s = 0.f;
  #pragma unroll 8
  for (int c = 0; c < 64; ++c) s += base[c * 128];
  float loss = __logf(s) - 2.0f * pos[gid & (B_ROWS - 1)];
  #pragma unroll
  for (int m = 1; m <= 32; m <<= 1) loss += __shfl_xor(loss, m);
  const int wave = threadIdx.x >> 6;
  const int lane = threadIdx.x & 63;
  if (lane == 0) red[wave] = loss;
  __syncthreads();
  if (threadIdx.x == 0)
    atomicAdd(out, (red[0] + red[1] + red[2] + red[3]) * (1.0f / NROWS));
}

extern "C" void kernel_launch(void* const* d_in, const int* in_sizes, int n_in,
                              void* d_out, int out_size, void* d_ws, size_t ws_size,
                              hipStream_t stream) {
  const float* h1 = (const float*)d_in[0];
  const float* h2 = (const float*)d_in[1];
  float* out = (float*)d_out;
  unsigned char* zq = (unsigned char*)d_ws;                        // 4 MiB fp8
  float* scratch = (float*)((char*)d_ws + (size_t)NROWS * DDIM);   // 2 MiB
  float* pos     = scratch + 64 * 64 * 128;                        // 16 KiB

  normalize_kernel<<<NROWS / 32, 256, 0, stream>>>(h1, h2, zq, out);
  simexp_kernel<<<64 * 65 / 2, 256, 0, stream>>>(zq, scratch, pos);
  finalize_kernel<<<NROWS / 256, 256, 0, stream>>>(scratch, pos, out);
}